// Round 10
// baseline (5932.814 us; speedup 1.0000x reference)
//
#include <hip/hip_runtime.h>

// Custom LSTM scan.  B=64, L=512, P=64, A=16, D=512, F=80.
//   h_t = h_{t-1} + tanh(x_t W_ci + b_ci) * sigmoid(h_{t-1} R_ig + b_ig)
// Round 10: intra-CU scan, one WG (512 thr) per batch row.  Output d by
// 8 lanes (k-slices of 64) reduced via DPP.  R chunks jc=0..63 per thread:
// 0..31 pinned VGPR ("+v"), 32..55 pinned AGPR ("+a", gfx950 unified file),
// 56..63 dynamic LDS.  NO L2 streaming in the loop (r6's 16-chunk stream
// ~1750 cy/step gone).  Single barrier/step with parity double-buffered h.
// r9 lesson: >32 "+v" chunks spill to scratch (WRITE_SIZE 2.3 MB) — AGPRs
// are the headroom, not more VGPRs.

#define B_  64
#define L_  512
#define P_  64
#define A_  16
#define D_  512
#define F_  80
#define CI_R 8

#define NLDS 8
#define SMEM_BYTES (NLDS * D_ * 16 + 2048 + 64 + 2048)

typedef _Float16 half2_t __attribute__((ext_vector_type(2)));

__device__ __forceinline__ float dot2(unsigned int r, unsigned int h, float acc) {
    return __builtin_amdgcn_fdot2(__builtin_bit_cast(half2_t, h),
                                  __builtin_bit_cast(half2_t, r), acc, false);
}
__device__ __forceinline__ float dot4u(uint4 r, uint4 h, float acc) {
    acc = dot2(r.x, h.x, acc);
    acc = dot2(r.y, h.y, acc);
    acc = dot2(r.z, h.z, acc);
    acc = dot2(r.w, h.w, acc);
    return acc;
}
template<int CTRL>
__device__ __forceinline__ float dpp_mov(float v) {
    return __builtin_bit_cast(float, __builtin_amdgcn_update_dpp(
        0, __builtin_bit_cast(int, v), CTRL, 0xF, 0xF, true));
}
// DPP: quad_perm(1,0,3,2)=0xB1 xor1; quad_perm(2,3,0,1)=0x4E xor2;
// row_half_mirror=0x141 xor7; row_mirror=0x140; row_bcast15=0x142; row_bcast31=0x143.

// Pack R_ig fp32[k][d] -> f16-pair uint chunks [w][jc][l][q]:
// uint4 (w,jc,l), j=jc>>3, c=jc&7, holds pairs p=g*32+c*4+{0..3}
// (k=2p,2p+1) of column d = w*64 + (l>>3)*8 + j, g=l&7.
__global__ __launch_bounds__(256) void prep_kernel(const float* __restrict__ R,
                                                   unsigned int* __restrict__ Rp) {
    int id = blockIdx.x * 256 + threadIdx.x;          // 131072 uints
    int q = id & 3;
    int l = (id >> 2) & 63;
    int c = (id >> 8) & 7;
    int j = (id >> 11) & 7;
    int w = id >> 14;
    int r = l >> 3, g = l & 7;
    int d = w * 64 + r * 8 + j;
    int p = g * 32 + c * 4 + q;
    int k0 = 2 * p;
    half2_t v;
    v.x = (_Float16)R[k0 * D_ + d];
    v.y = (_Float16)R[(k0 + 1) * D_ + d];
    Rp[id] = __builtin_bit_cast(unsigned int, v);
}

// ci = tanh(x @ W_ci + b_ci), stored f16.
__global__ __launch_bounds__(256) void ci_kernel(const float* __restrict__ obs,
                                                 const float* __restrict__ act,
                                                 const float* __restrict__ W,
                                                 const float* __restrict__ bci,
                                                 unsigned short* __restrict__ ci) {
    __shared__ float xs[CI_R][F_];
    int row0 = blockIdx.x * CI_R;
    int tid = threadIdx.x;
    for (int idx = tid; idx < CI_R * F_; idx += 256) {
        int r = idx / F_, f = idx % F_;
        float v = (f < P_) ? obs[(size_t)(row0 + r) * P_ + f]
                           : act[(size_t)(row0 + r) * A_ + (f - P_)];
        xs[r][f] = v;
    }
    __syncthreads();
    int d0 = tid, d1 = tid + 256;
    float a0[CI_R], a1[CI_R];
    #pragma unroll
    for (int r = 0; r < CI_R; ++r) { a0[r] = 0.f; a1[r] = 0.f; }
    for (int f = 0; f < F_; ++f) {
        float w0 = W[f * D_ + d0];
        float w1 = W[f * D_ + d1];
        #pragma unroll
        for (int r = 0; r < CI_R; ++r) {
            float xv = xs[r][f];
            a0[r] += xv * w0;
            a1[r] += xv * w1;
        }
    }
    float b0 = bci[d0], b1 = bci[d1];
    #pragma unroll
    for (int r = 0; r < CI_R; ++r) {
        float z0 = a0[r] + b0, z1 = a1[r] + b1;
        float e0 = __expf(-2.f * __builtin_fabsf(z0));
        float e1 = __expf(-2.f * __builtin_fabsf(z1));
        float m0 = (1.f - e0) * __builtin_amdgcn_rcpf(1.f + e0);
        float m1 = (1.f - e1) * __builtin_amdgcn_rcpf(1.f + e1);
        float t0 = z0 < 0.f ? -m0 : m0;
        float t1 = z1 < 0.f ? -m1 : m1;
        ci[(size_t)(row0 + r) * D_ + d0] = __builtin_bit_cast(unsigned short, (_Float16)t0);
        ci[(size_t)(row0 + r) * D_ + d1] = __builtin_bit_cast(unsigned short, (_Float16)t1);
    }
}

// Serial scan.  One block per batch row.  Thread (w=tid>>6, l=tid&63), g=l&7:
// partials over k in [g*64,g*64+64) for outputs d = w*64+(l>>3)*8+j, j=0..7;
// DPP reduce-scatter -> thread owns d=tid.  jc map: 0..31 VGPR, 32..55 AGPR,
// 56..63 LDS.  No global R traffic inside the t-loop.
__global__ __launch_bounds__(512)
__attribute__((amdgpu_waves_per_eu(2, 2)))
void scan_kernel(
    const uint4* __restrict__ Rp, const unsigned short* __restrict__ ci,
    const float* __restrict__ b_ig, const float* __restrict__ W_out,
    const float* __restrict__ b_out, float* __restrict__ out)
{
    const int tid = threadIdx.x;
    const int b = blockIdx.x;
    const int w = tid >> 6;
    const int l = tid & 63;
    const int g = l & 7;

    extern __shared__ __align__(16) char smem[];
    uint4* ldsR = (uint4*)smem;                                     // 8*512*16
    unsigned int* hpbuf = (unsigned int*)(smem + NLDS * D_ * 16);   // 2*1024 B
    float* redbuf = (float*)(smem + NLDS * D_ * 16 + 2048);         // 2*32 B
    float* outbuf = (float*)(smem + NLDS * D_ * 16 + 2112);         // 2048 B

    const uint4* tb = Rp + (w << 12) + l;   // chunk jc at tb[jc*64]

    // 32 chunks (jc 0..31, j=0..3) pinned in VGPRs
    uint4 rv[32];
    #pragma unroll
    for (int i = 0; i < 32; ++i) rv[i] = tb[i * 64];
    #pragma unroll
    for (int i = 0; i < 32; ++i)
        asm volatile("" : "+v"(rv[i].x), "+v"(rv[i].y), "+v"(rv[i].z), "+v"(rv[i].w));

    // 24 chunks (jc 32..55, j=4..6) pinned in AGPRs (unified file headroom)
    uint4 ra[24];
    #pragma unroll
    for (int i = 0; i < 24; ++i) ra[i] = tb[(32 + i) * 64];
    #pragma unroll
    for (int i = 0; i < 24; ++i)
        asm volatile("" : "+a"(ra[i].x), "+a"(ra[i].y), "+a"(ra[i].z), "+a"(ra[i].w));

    // 8 chunks (jc 56..63, j=7) in LDS
    #pragma unroll
    for (int i = 0; i < NLDS; ++i) ldsR[i * D_ + tid] = tb[(56 + i) * 64];
    if (tid < 256) hpbuf[tid] = 0u;        // h parity-buffer 0 = zeros

    float hval = 0.f;
    const float bg = b_ig[tid];
    const float wo = W_out[tid];
    const float bo = b_out[0];
    const unsigned short* cip = ci + (size_t)b * L_ * D_ + tid;

    // swizzled h write slot within a 256-uint buffer (conflict-free reads)
    const int wslot = (((w << 3) | ((((tid >> 3) & 7) + w) & 7)) << 2) | ((tid >> 1) & 3);

    __syncthreads();

    #pragma unroll 1
    for (int t = 0; t < L_; ++t) {
        const unsigned int* hpc = hpbuf + (t & 1) * 256;        // read buffer
        unsigned int* hpn = hpbuf + ((t & 1) ^ 1) * 256;        // write buffer
        float* redc = redbuf + (t & 1) * 8;

        // finish step t-1's output row (parity-disjoint from this epoch)
        if (t > 0 && tid == 0) {
            const float* rp = redbuf + ((t - 1) & 1) * 8;
            outbuf[t - 1] = rp[0] + rp[1] + rp[2] + rp[3] +
                            rp[4] + rp[5] + rp[6] + rp[7] + bo;
        }

        unsigned short cu = cip[t * D_];

        // h slice (8 uint4) from swizzled parity buffer
        const uint4* hp4s = (const uint4*)hpc;
        uint4 hsr[8];
        #pragma unroll
        for (int c = 0; c < 8; ++c) hsr[c] = hp4s[(g << 3) | ((c + g) & 7)];

        float p[8];
        #pragma unroll
        for (int j = 0; j < 8; ++j) p[j] = 0.f;

        // VGPR chunks: j=0..3
        #pragma unroll
        for (int i = 0; i < 32; ++i) p[i >> 3] = dot4u(rv[i], hsr[i & 7], p[i >> 3]);

        // AGPR chunks: j=4..6
        #pragma unroll
        for (int i = 0; i < 24; ++i) p[4 + (i >> 3)] = dot4u(ra[i], hsr[i & 7], p[4 + (i >> 3)]);

        // LDS chunks: j=7
        #pragma unroll
        for (int i = 0; i < NLDS; ++i) p[7] = dot4u(ldsR[i * D_ + tid], hsr[i], p[7]);

        // DPP reduce-scatter across the 8-lane slice group
        float q0[4];
        #pragma unroll
        for (int i = 0; i < 4; ++i) {
            float a = p[i] + dpp_mov<0x141>(p[i]);       // xor7
            float c2 = p[i + 4] + dpp_mov<0x141>(p[i + 4]);
            q0[i] = (g & 4) ? c2 : a;
        }
        float r0a = q0[0] + dpp_mov<0xB1>(q0[0]);        // xor1
        float r0b = q0[1] + dpp_mov<0xB1>(q0[1]);
        float r1a = q0[2] + dpp_mov<0xB1>(q0[2]);
        float r1b = q0[3] + dpp_mov<0xB1>(q0[3]);
        float r0 = (g & 1) ? r0b : r0a;
        float r1 = (g & 1) ? r1b : r1a;
        float za = r0 + dpp_mov<0x4E>(r0);               // xor2
        float zb = r1 + dpp_mov<0x4E>(r1);
        float z = (g & 2) ? zb : za;                     // z for d = tid

        float zz = z + bg;
        float ig = __builtin_amdgcn_rcpf(1.f + __expf(-zz));
        float civ = (float)__builtin_bit_cast(_Float16, cu);
        hval += civ * ig;

        // out-projection partial (sum lands in lane 63)
        float po = hval * wo;
        po += dpp_mov<0xB1>(po);
        po += dpp_mov<0x4E>(po);
        po += dpp_mov<0x141>(po);
        po += dpp_mov<0x140>(po);
        po += dpp_mov<0x142>(po);
        po += dpp_mov<0x143>(po);

        float nbh = dpp_mov<0xB1>(hval);  // h[tid^1]

        // write new h into the parity write-buffer (disjoint from reads;
        // safe with a single barrier: the next epoch's writes can only
        // happen after every wave passes this epoch's barrier)
        if ((tid & 1) == 0) {
            hpn[wslot] = __builtin_bit_cast(unsigned int,
                             __builtin_amdgcn_cvt_pkrtz(hval, nbh));
        }
        if (l == 63) redc[w] = po;
        __syncthreads();                  // single barrier per step
    }
    if (tid == 0) {
        const float* rp = redbuf + ((L_ - 1) & 1) * 8;
        outbuf[L_ - 1] = rp[0] + rp[1] + rp[2] + rp[3] +
                         rp[4] + rp[5] + rp[6] + rp[7] + bo;
    }
    __syncthreads();
    out[b * L_ + tid] = outbuf[tid];
}

extern "C" void kernel_launch(void* const* d_in, const int* in_sizes, int n_in,
                              void* d_out, int out_size, void* d_ws, size_t ws_size,
                              hipStream_t stream) {
    const float* obs   = (const float*)d_in[0];
    const float* act   = (const float*)d_in[1];
    const float* W_ci  = (const float*)d_in[2];
    const float* b_ci  = (const float*)d_in[3];
    const float* R_ig  = (const float*)d_in[4];
    const float* b_ig  = (const float*)d_in[5];
    const float* W_out = (const float*)d_in[6];
    const float* b_out = (const float*)d_in[7];
    float* out = (float*)d_out;

    unsigned short* ci = (unsigned short*)d_ws;                        // 32 MB f16
    unsigned int* Rp = (unsigned int*)((char*)d_ws + (size_t)B_ * L_ * D_ * 2);

    hipFuncSetAttribute((const void*)scan_kernel,
                        hipFuncAttributeMaxDynamicSharedMemorySize, SMEM_BYTES);

    prep_kernel<<<512, 256, 0, stream>>>(R_ig, Rp);
    ci_kernel<<<(B_ * L_) / CI_R, 256, 0, stream>>>(obs, act, W_ci, b_ci, ci);
    scan_kernel<<<B_, D_, SMEM_BYTES, stream>>>((const uint4*)Rp, ci, b_ig, W_out, b_out, out);
}